// Round 4
// baseline (2995.057 us; speedup 1.0000x reference)
//
#include <hip/hip_runtime.h>

static constexpr int BATCH = 512;
static constexpr int TT    = 1020;   // conv output length (1024 - 5 + 1)
static constexpr int MM    = BATCH * TT;  // 522240 rows for xg GEMMs

typedef float f2 __attribute__((ext_vector_type(2)));   // -> v_pk_fma_f32

// ---- fast device nonlinearities (1-ulp hw exp2/rcp; fine vs 1.76e-3 budget) ----
__device__ __forceinline__ float fsig(float x) {
  float e = __builtin_amdgcn_exp2f(x * -1.442695041f);
  return __builtin_amdgcn_rcpf(1.0f + e);
}
__device__ __forceinline__ float ftanh(float x) {
  float e = __builtin_amdgcn_exp2f(x * 2.885390082f); // e^(2x)
  return 1.0f - 2.0f * __builtin_amdgcn_rcpf(e + 1.0f);
}

// =====================================================================
// conv1d valid, K=5: x[512][128][1024] (*) w[128][128][5] + b -> c[512][128][1020]
// R3: VALU-issue-bound (77% busy, FMA floor 546us). Fix: v_pk_fma_f32 via
// float2 elementwise fma halves FMA issue. Pitch 264 (= 8 mod 32) makes the
// staging writes exactly 2-way (free) — kills the persistent 1.43e8 conflicts.
// =====================================================================
__global__ __launch_bounds__(256, 4) void conv_kernel(
    const float* __restrict__ x, const float* __restrict__ w,
    const float* __restrict__ bias, float* __restrict__ c) {
  __shared__ float xs[32][264];    // 33,792 B -> 4 blocks/CU
  const int b   = blockIdx.z;
  const int co0 = blockIdx.y * 32;
  const int l0  = blockIdx.x * 256;
  const int tid = threadIdx.x;
  const int lid = tid & 63;   // l = l0 + lid*4 + j   (j = 0..3)
  const int wid = __builtin_amdgcn_readfirstlane(tid >> 6);
  const float* wbase = w + (size_t)(co0 + wid * 8) * 640;

  f2 acc2[8][2];
#pragma unroll
  for (int i = 0; i < 8; ++i) { acc2[i][0] = f2{0.f, 0.f}; acc2[i][1] = f2{0.f, 0.f}; }

  for (int ci0 = 0; ci0 < 128; ci0 += 32) {
    __syncthreads();
    // --- stage x chunk: thread (ci=tid>>3, j0=tid&7), b32 writes, 2-way free ---
    {
      const int ci = tid >> 3;
      const int j0 = tid & 7;
      const float* xrow = x + ((size_t)b * 128 + ci0 + ci) * 1024 + l0;
      for (int j = j0; j < 260; j += 8)
        xs[ci][j] = (l0 + j < 1024) ? xrow[j] : 0.f;
    }
    __syncthreads();
    // --- compute: per ci, 2 conflict-free b128 LDS reads; w via s_load ---
#pragma unroll 2
    for (int ci = 0; ci < 32; ++ci) {
      float xv[8];
      *(float4*)&xv[0] = *(const float4*)&xs[ci][lid * 4];
      *(float4*)&xv[4] = *(const float4*)&xs[ci][lid * 4 + 4];
      float wv[8][5];   // wave-uniform -> SGPRs via s_load
#pragma unroll
      for (int cc = 0; cc < 8; ++cc)
#pragma unroll
        for (int k = 0; k < 5; ++k)
          wv[cc][k] = wbase[(size_t)cc * 640 + (ci0 + ci) * 5 + k];
#pragma unroll
      for (int k = 0; k < 5; ++k) {
        const f2 xp0 = {xv[k], xv[k + 1]};
        const f2 xp1 = {xv[k + 2], xv[k + 3]};
#pragma unroll
        for (int cc = 0; cc < 8; ++cc) {
          const f2 ws = {wv[cc][k], wv[cc][k]};
          acc2[cc][0] = __builtin_elementwise_fma(ws, xp0, acc2[cc][0]);
          acc2[cc][1] = __builtin_elementwise_fma(ws, xp1, acc2[cc][1]);
        }
      }
    }
  }
  // --- store: float4 per co row ---
  const int l = l0 + lid * 4;
  if (l < TT) {
#pragma unroll
    for (int cc = 0; cc < 8; ++cc) {
      const int co = co0 + wid * 8 + cc;
      const float bv = bias[co];
      float* crow = c + (size_t)b * 130560 + (size_t)co * TT;
      float4 st;
      st.x = acc2[cc][0].x + bv; st.y = acc2[cc][0].y + bv;
      st.z = acc2[cc][1].x + bv; st.w = acc2[cc][1].y + bv;
      *(float4*)(crow + l) = st;
    }
  }
}

// =====================================================================
// xg GEMM: A[MM][K] @ W[NT][K]^T + (bih+bhh) -> xgT[b][n][t] (transposed).
// R4 rewrite: 128m x NT block (grid covers all n in one block), 8m x (NT/16)n
// per-thread tile, pk_fma inner loop. LDS uses XOR swizzle at 16B granularity
// (cb ^= (k>>1)&7): staging's transposed column-writes drop from 32-way
// conflicts (old pitch-68 layout: 2 banks!) to 4-way; main-loop b128 reads
// stay aligned and conflict-free (A reads are 16-lane broadcasts).
// =====================================================================
template <int K, int NT>
__global__ __launch_bounds__(256) void gemm_xg(
    const float* __restrict__ A, const float* __restrict__ W,
    const float* __restrict__ bih, const float* __restrict__ bhh,
    float* __restrict__ xgT) {
  constexpr int KC   = (K > 64) ? 64 : K;
  constexpr int NREG = NT / 16;          // 8 (NT=128) or 4 (NT=64)
  constexpr int LA   = (128 * KC) / 1024;
  constexpr int LW   = (NT * KC) / 1024;
  __shared__ float At[KC][128];
  __shared__ float Wt[KC][NT];
  const int m0  = blockIdx.x * 128;
  const int tid = threadIdx.x;
  const int tn  = tid & 15;   // n quads at 4*tn (+64)
  const int tm  = tid >> 4;   // m quads at 4*tm (+64)

  f2 acc2[8][NREG / 2];
#pragma unroll
  for (int i = 0; i < 8; ++i)
#pragma unroll
    for (int j = 0; j < NREG / 2; ++j) acc2[i][j] = f2{0.f, 0.f};

  for (int kc = 0; kc < K; kc += KC) {
    __syncthreads();
    // ---- stage A tile (128 x KC), swizzled transpose ----
#pragma unroll
    for (int it = 0; it < LA; ++it) {
      const int i  = tid + it * 256;
      const int r  = i / (KC / 4);
      const int c4 = i - r * (KC / 4);
      const float4 v = *(const float4*)(A + (size_t)(m0 + r) * K + kc + c4 * 4);
      const int rb = r >> 2, rr = r & 3;
#pragma unroll
      for (int comp = 0; comp < 4; ++comp) {
        const int k = c4 * 4 + comp;
        At[k][4 * (rb ^ ((k >> 1) & 7)) + rr] = ((const float*)&v)[comp];
      }
    }
    // ---- stage W tile (NT x KC), swizzled transpose ----
#pragma unroll
    for (int it = 0; it < LW; ++it) {
      const int i  = tid + it * 256;
      const int r  = i / (KC / 4);
      const int c4 = i - r * (KC / 4);
      const float4 v = *(const float4*)(W + (size_t)r * K + kc + c4 * 4);
      const int rb = r >> 2, rr = r & 3;
#pragma unroll
      for (int comp = 0; comp < 4; ++comp) {
        const int k = c4 * 4 + comp;
        Wt[k][4 * (rb ^ ((k >> 1) & 7)) + rr] = ((const float*)&v)[comp];
      }
    }
    __syncthreads();
    // ---- main loop ----
#pragma unroll 2
    for (int k = 0; k < KC; ++k) {
      const int s  = (k >> 1) & 7;
      const int mq = 4 * (tm ^ s);
      const int nq = 4 * (tn ^ s);
      float a[8];
      *(float4*)&a[0] = *(const float4*)&At[k][mq];
      *(float4*)&a[4] = *(const float4*)&At[k][64 + mq];
      f2 wp[NREG / 2];
      {
        const float4 w0 = *(const float4*)&Wt[k][nq];
        wp[0] = f2{w0.x, w0.y}; wp[1] = f2{w0.z, w0.w};
        if constexpr (NREG == 8) {
          const float4 w1 = *(const float4*)&Wt[k][64 + nq];
          wp[2] = f2{w1.x, w1.y}; wp[3] = f2{w1.z, w1.w};
        }
      }
#pragma unroll
      for (int i8 = 0; i8 < 8; ++i8) {
        const f2 as = {a[i8], a[i8]};
#pragma unroll
        for (int jp = 0; jp < NREG / 2; ++jp)
          acc2[i8][jp] = __builtin_elementwise_fma(as, wp[jp], acc2[i8][jp]);
      }
    }
  }
  // ---- epilogue: bias + transposed scatter (exact magic div by 1020) ----
  float bv[NREG];
#pragma unroll
  for (int j = 0; j < NREG; ++j) {
    const int n = (NREG == 8) ? ((j >> 2) * 64 + 4 * tn + (j & 3)) : (4 * tn + j);
    bv[j] = bih[n] + bhh[n];
  }
#pragma unroll
  for (int i8 = 0; i8 < 8; ++i8) {
    const int m  = m0 + (i8 >> 2) * 64 + 4 * tm + (i8 & 3);
    const int bb = (int)(((unsigned long long)m * 4311810306ULL) >> 42); // m/1020
    const int t  = m - bb * TT;
#pragma unroll
    for (int j = 0; j < NREG; ++j) {
      const int n = (NREG == 8) ? ((j >> 2) * 64 + 4 * tn + (j & 3)) : (4 * tn + j);
      xgT[((size_t)bb * NT + n) * TT + t] =
          ((const float*)&acc2[i8][j >> 1])[j & 1] + bv[j];
    }
  }
}

// =====================================================================
// LSTM recurrence: one wave per batch element (unchanged from R3).
// =====================================================================
template <int H, bool FINAL>
__global__ __launch_bounds__(64) void lstm_kernel(
    const float* __restrict__ xgT, const float* __restrict__ Whh,
    float* __restrict__ hout) {
  constexpr int G   = 4 * H;
  constexpr int GPL = G / 64;  // 2 for H=32, 1 for H=16
  constexpr int KG  = H / 4;   // k-group size
  const int b    = blockIdx.x;
  const int lane = threadIdx.x;
  const int g0 = lane;
  const int g1 = lane + 64;

  float w0[H];
  float w1[GPL == 2 ? H : 1];
#pragma unroll
  for (int k = 0; k < H; ++k) {
    w0[k] = Whh[g0 * H + k];
    if constexpr (GPL == 2) w1[k] = Whh[g1 * H + k];
  }

  const float* p0 = xgT + ((size_t)b * G + g0) * TT;
  const float* p1 = xgT + ((size_t)b * G + (GPL == 2 ? g1 : g0)) * TT;

  float h = 0.f, c = 0.f;
  float4 cur0[4], cur1[4], nxt0[4], nxt1[4];
#pragma unroll
  for (int r = 0; r < 4; ++r) {
    cur0[r] = *(const float4*)(p0 + 4 * r);
    nxt0[r] = *(const float4*)(p0 + 16 + 4 * r);
    if constexpr (GPL == 2) {
      cur1[r] = *(const float4*)(p1 + 4 * r);
      nxt1[r] = *(const float4*)(p1 + 16 + 4 * r);
    }
  }

  for (int t16 = 0; t16 < TT; t16 += 16) {
#pragma unroll
    for (int r = 0; r < 4; ++r) {
      const int t4 = t16 + 4 * r;
      if (t4 >= TT) break;   // tail: TT=1020 = 63*16 + 12
#pragma unroll
      for (int s = 0; s < 4; ++s) {
        float q0[4], q1[4];
        q0[0] = ((const float*)&cur0[r])[s]; q0[1] = 0.f; q0[2] = 0.f; q0[3] = 0.f;
        if constexpr (GPL == 2) {
          q1[0] = ((const float*)&cur1[r])[s]; q1[1] = 0.f; q1[2] = 0.f; q1[3] = 0.f;
        }
#pragma unroll
        for (int g = 0; g < 4; ++g)
#pragma unroll
          for (int k8 = 0; k8 < KG; ++k8) {
            const int k = g * KG + k8;
            const float hk =
                __uint_as_float(__builtin_amdgcn_readlane(__float_as_uint(h), k));
            q0[g] = fmaf(w0[k], hk, q0[g]);
            if constexpr (GPL == 2) q1[g] = fmaf(w1[k], hk, q1[g]);
          }
        const float acc0 = (q0[0] + q0[1]) + (q0[2] + q0[3]);
        float acc1 = 0.f;
        if constexpr (GPL == 2) acc1 = (q1[0] + q1[1]) + (q1[2] + q1[3]);

        float iraw, fraw, graw, oraw;
        if constexpr (H == 32) {
          const float r0 = __shfl_xor(acc0, 32, 64);
          const float r1 = __shfl_xor(acc1, 32, 64);
          const bool hi = lane >= 32;
          iraw = hi ? r0 : acc0;
          fraw = hi ? acc0 : r0;
          graw = hi ? r1 : acc1;
          oraw = hi ? acc1 : r1;
        } else {
          const float x1 = __shfl_xor(acc0, 16, 64);
          const float x2 = __shfl_xor(acc0, 32, 64);
          const float x3 = __shfl_xor(acc0, 48, 64);
          const int q = lane >> 4;
          const float t0 = (q & 1) ? x1 : acc0;
          const float t1 = (q & 1) ? acc0 : x1;
          const float u0 = (q & 1) ? x3 : x2;
          const float u1 = (q & 1) ? x2 : x3;
          const bool hi2 = q >= 2;
          iraw = hi2 ? u0 : t0;
          fraw = hi2 ? u1 : t1;
          graw = hi2 ? t0 : u0;
          oraw = hi2 ? t1 : u1;
        }
        const float ig = fsig(iraw);
        const float fg = fsig(fraw);
        const float gg = ftanh(graw);
        const float og = fsig(oraw);
        c = fmaf(fg, c, ig * gg);
        h = og * ftanh(c);
        if constexpr (!FINAL) {
          if (lane < H) hout[((size_t)b * TT + (t4 + s)) * H + lane] = h;
        } else {
          if (t4 + s == TT - 1 && lane < H) hout[b * H + lane] = h;
        }
      }
    }
#pragma unroll
    for (int r = 0; r < 4; ++r) {
      cur0[r] = nxt0[r];
      if constexpr (GPL == 2) cur1[r] = nxt1[r];
      const int tp = t16 + 32 + 4 * r;
      if (tp < TT) {
        nxt0[r] = *(const float4*)(p0 + tp);
        if constexpr (GPL == 2) nxt1[r] = *(const float4*)(p1 + tp);
      }
    }
  }
}

// =====================================================================
extern "C" void kernel_launch(void* const* d_in, const int* in_sizes, int n_in,
                              void* d_out, int out_size, void* d_ws, size_t ws_size,
                              hipStream_t stream) {
  const float* x      = (const float*)d_in[0];
  const float* conv_w = (const float*)d_in[1];
  const float* conv_b = (const float*)d_in[2];
  const float* Wih1   = (const float*)d_in[3];
  const float* Whh1   = (const float*)d_in[4];
  const float* bih1   = (const float*)d_in[5];
  const float* bhh1   = (const float*)d_in[6];
  const float* Wih2   = (const float*)d_in[7];
  const float* Whh2   = (const float*)d_in[8];
  const float* bih2   = (const float*)d_in[9];
  const float* bhh2   = (const float*)d_in[10];
  const float* Wih3   = (const float*)d_in[11];
  const float* Whh3   = (const float*)d_in[12];
  const float* bih3   = (const float*)d_in[13];
  const float* bhh3   = (const float*)d_in[14];
  float* out = (float*)d_out;
  float* ws  = (float*)d_ws;

  float* c    = ws;                    // conv out == seq (flat view)
  float* xgT1 = ws + 66846720;
  float* h1   = ws + 133693440;
  float* xgT2 = c;                     // reuse conv region
  float* h2   = h1;                    // reuse h1 region
  float* xgT3 = xgT1;                  // reuse xgT1 region

  conv_kernel<<<dim3(4, 4, BATCH), 256, 0, stream>>>(x, conv_w, conv_b, c);
  gemm_xg<128, 128><<<MM / 128, 256, 0, stream>>>(c, Wih1, bih1, bhh1, xgT1);
  lstm_kernel<32, false><<<BATCH, 64, 0, stream>>>(xgT1, Whh1, h1);
  gemm_xg<32, 64><<<MM / 128, 256, 0, stream>>>(h1, Wih2, bih2, bhh2, xgT2);
  lstm_kernel<16, false><<<BATCH, 64, 0, stream>>>(xgT2, Whh2, h2);
  gemm_xg<16, 128><<<MM / 128, 256, 0, stream>>>(h2, Wih3, bih3, bhh3, xgT3);
  lstm_kernel<32, true><<<BATCH, 64, 0, stream>>>(xgT3, Whh3, out);
}